// Round 8
// baseline (43.262 us; speedup 1.0000x reference)
//
#include <hip/hip_runtime.h>

#define B_  4
#define NQ_ 256
#define NK_ 512
#define H_  256

// tanh(x) = 1 - 2/(exp2(x*2*log2e)+1), clamped strictly inside (-1,1) so the
// tanh-addition denominator 1+ta*tb is always > 0.
#define TWO_LOG2E 2.8853900817779268f
__device__ __forceinline__ float tanh_fast(float x) {
    float t = __builtin_amdgcn_exp2f(x * TWO_LOG2E);
    float r = __builtin_amdgcn_rcpf(t + 1.0f);
    float y = fmaf(-2.0f, r, 1.0f);
    return fminf(fmaxf(y, -0.99999994f), 0.99999994f);
}

// Both GEMMs, 32x64 tiles, 256 threads, 8 outputs/thread (4m x 2n).
// Register-double-buffered global->LDS pipeline.
// blocks [0,256):  kt[b][o][k] -> ktTan[b][o>>2][k][o&3] = tanh(kt)
// blocks [256,384): qt[b][q][o] -> tbT[b][q][o] = tanh(qt)
__global__ __launch_bounds__(256)
void gemm_fused(const float* __restrict__ xq, const float* __restrict__ xk,
                const float* __restrict__ w1, const float* __restrict__ w2,
                float* __restrict__ ktTan,   // [B][H/4][NK][4]
                float* __restrict__ tbT)     // [B][NQ][H]
{
    constexpr int BK = 32;
    const float* A; const float* Bm;
    int m0, n0, bz; bool iskt;
    {
        int id = blockIdx.x;
        if (id < 256) {                      // kt: M=H(o), N=NK(k)
            iskt = true;
            bz = id >> 6; int t = id & 63;
            m0 = (t >> 3) * 32; n0 = (t & 7) * 64;
            A = w1; Bm = xk + (long)bz * NK_ * H_;
        } else {                             // qt: M=NQ(q), N=H(o)
            iskt = false;
            id -= 256;
            bz = id >> 5; int t = id & 31;
            m0 = (t >> 2) * 32; n0 = (t & 3) * 64;
            A = xq + (long)bz * NQ_ * H_; Bm = w2;
        }
    }
    const int lda = H_, ldb = H_;

    __shared__ float As[BK][36];
    __shared__ float Bs[BK][68];

    const int tid  = threadIdx.x;
    const int arow = tid >> 3, ak = (tid & 7) * 4;
    const int brow = tid >> 2, bk = (tid & 3) * 8;
    const int tm = (tid >> 5) * 4;       // 0..28
    const int tn = (tid & 31) * 2;       // 0..62

    float acc[4][2] = {};

    float4 a_r  = *(const float4*)&A [(long)(m0 + arow) * lda + ak];
    float4 b0_r = *(const float4*)&Bm[(long)(n0 + brow) * ldb + bk];
    float4 b1_r = *(const float4*)&Bm[(long)(n0 + brow) * ldb + bk + 4];
    float4 a_n, b0_n, b1_n;

    for (int kt = 0; kt < H_; kt += BK) {
        __syncthreads();
        As[ak+0][arow]=a_r.x; As[ak+1][arow]=a_r.y; As[ak+2][arow]=a_r.z; As[ak+3][arow]=a_r.w;
        Bs[bk+0][brow]=b0_r.x; Bs[bk+1][brow]=b0_r.y; Bs[bk+2][brow]=b0_r.z; Bs[bk+3][brow]=b0_r.w;
        Bs[bk+4][brow]=b1_r.x; Bs[bk+5][brow]=b1_r.y; Bs[bk+6][brow]=b1_r.z; Bs[bk+7][brow]=b1_r.w;
        if (kt + BK < H_) {
            a_n  = *(const float4*)&A [(long)(m0 + arow) * lda + kt + BK + ak];
            b0_n = *(const float4*)&Bm[(long)(n0 + brow) * ldb + kt + BK + bk];
            b1_n = *(const float4*)&Bm[(long)(n0 + brow) * ldb + kt + BK + bk + 4];
        }
        __syncthreads();
        #pragma unroll
        for (int kk = 0; kk < BK; ++kk) {
            float4 av = *(const float4*)&As[kk][tm];
            float2 bv = *(const float2*)&Bs[kk][tn];
            float am[4] = {av.x, av.y, av.z, av.w};
            #pragma unroll
            for (int i = 0; i < 4; ++i) {
                acc[i][0] = fmaf(am[i], bv.x, acc[i][0]);
                acc[i][1] = fmaf(am[i], bv.y, acc[i][1]);
            }
        }
        a_r = a_n; b0_r = b0_n; b1_r = b1_n;
    }

    if (iskt) {
        float* cb = ktTan + (long)bz * H_ * NK_ + (long)((m0 + tm) >> 2) * (NK_ * 4);
        #pragma unroll
        for (int j = 0; j < 2; ++j) {
            float4 t4 = { tanh_fast(acc[0][j]), tanh_fast(acc[1][j]),
                          tanh_fast(acc[2][j]), tanh_fast(acc[3][j]) };
            *(float4*)&cb[(n0 + tn + j) * 4] = t4;
        }
    } else {
        #pragma unroll
        for (int i = 0; i < 4; ++i) {
            float2 t2 = { tanh_fast(acc[i][0]), tanh_fast(acc[i][1]) };
            long off = ((long)bz * NQ_ + m0 + tm + i) * H_ + n0 + tn;
            *(float2*)&tbT[off] = t2;
        }
    }
}

// One block per (b, 4 q-rows), 512 threads = one per k. Explicit 4-deep kv
// register prefetch + __launch_bounds__(512,1) so the compiler has VGPR room
// to keep loads in flight (rounds 3-7 compiled to ~20 VGPR -> load-use
// stalls every iteration). Per element: p = v*(ta+tb), d = fma(ta,tb,1);
// 4 terms share one rcp via a common-denominator tree.
__global__ __launch_bounds__(512, 1)
void attn_main(const float4* __restrict__ kt4,  // [B][H/4][NK] float4s
               const float4* __restrict__ tbT,  // [B][NQ][H/4]
               const float4* __restrict__ v4p,  // [H/4]
               float* __restrict__ out)         // [B][NQ][NK]
{
    const int k = threadIdx.x, b = blockIdx.y, q0 = blockIdx.x * 4;
    const float4* kp  = kt4 + (long)b * (H_ / 4) * NK_ + k;
    const float4* t0p = tbT + ((long)b * NQ_ + q0) * (H_ / 4);
    const float4* t1p = t0p + (H_ / 4);
    const float4* t2p = t1p + (H_ / 4);
    const float4* t3p = t2p + (H_ / 4);

    float ac0 = 0.f, ac1 = 0.f, ac2 = 0.f, ac3 = 0.f;

    // 4-deep kv prefetch queue (statically named)
    float4 kv0 = kp[0 * NK_], kv1 = kp[1 * NK_], kv2 = kp[2 * NK_], kv3 = kp[3 * NK_];
    float4 n0, n1, n2, n3;

#define PROC(TA, HC)                                                          \
    {                                                                         \
        float4 vv = v4p[HC];                                                  \
        {   float4 tb = t0p[HC];                                              \
            float d0 = fmaf(TA.x, tb.x, 1.f), d1 = fmaf(TA.y, tb.y, 1.f);     \
            float d2 = fmaf(TA.z, tb.z, 1.f), d3 = fmaf(TA.w, tb.w, 1.f);     \
            float p0 = vv.x * (TA.x + tb.x), p1 = vv.y * (TA.y + tb.y);       \
            float p2 = vv.z * (TA.z + tb.z), p3 = vv.w * (TA.w + tb.w);       \
            float D01 = d0 * d1, D23 = d2 * d3;                               \
            float N01 = fmaf(p0, d1, p1 * d0);                                \
            float N23 = fmaf(p2, d3, p3 * d2);                                \
            float N   = fmaf(N01, D23, N23 * D01);                            \
            ac0 = fmaf(N, __builtin_amdgcn_rcpf(D01 * D23), ac0);             \
        }                                                                     \
        {   float4 tb = t1p[HC];                                              \
            float d0 = fmaf(TA.x, tb.x, 1.f), d1 = fmaf(TA.y, tb.y, 1.f);     \
            float d2 = fmaf(TA.z, tb.z, 1.f), d3 = fmaf(TA.w, tb.w, 1.f);     \
            float p0 = vv.x * (TA.x + tb.x), p1 = vv.y * (TA.y + tb.y);       \
            float p2 = vv.z * (TA.z + tb.z), p3 = vv.w * (TA.w + tb.w);       \
            float D01 = d0 * d1, D23 = d2 * d3;                               \
            float N01 = fmaf(p0, d1, p1 * d0);                                \
            float N23 = fmaf(p2, d3, p3 * d2);                                \
            float N   = fmaf(N01, D23, N23 * D01);                            \
            ac1 = fmaf(N, __builtin_amdgcn_rcpf(D01 * D23), ac1);             \
        }                                                                     \
        {   float4 tb = t2p[HC];                                              \
            float d0 = fmaf(TA.x, tb.x, 1.f), d1 = fmaf(TA.y, tb.y, 1.f);     \
            float d2 = fmaf(TA.z, tb.z, 1.f), d3 = fmaf(TA.w, tb.w, 1.f);     \
            float p0 = vv.x * (TA.x + tb.x), p1 = vv.y * (TA.y + tb.y);       \
            float p2 = vv.z * (TA.z + tb.z), p3 = vv.w * (TA.w + tb.w);       \
            float D01 = d0 * d1, D23 = d2 * d3;                               \
            float N01 = fmaf(p0, d1, p1 * d0);                                \
            float N23 = fmaf(p2, d3, p3 * d2);                                \
            float N   = fmaf(N01, D23, N23 * D01);                            \
            ac2 = fmaf(N, __builtin_amdgcn_rcpf(D01 * D23), ac2);             \
        }                                                                     \
        {   float4 tb = t3p[HC];                                              \
            float d0 = fmaf(TA.x, tb.x, 1.f), d1 = fmaf(TA.y, tb.y, 1.f);     \
            float d2 = fmaf(TA.z, tb.z, 1.f), d3 = fmaf(TA.w, tb.w, 1.f);     \
            float p0 = vv.x * (TA.x + tb.x), p1 = vv.y * (TA.y + tb.y);       \
            float p2 = vv.z * (TA.z + tb.z), p3 = vv.w * (TA.w + tb.w);       \
            float D01 = d0 * d1, D23 = d2 * d3;                               \
            float N01 = fmaf(p0, d1, p1 * d0);                                \
            float N23 = fmaf(p2, d3, p3 * d2);                                \
            float N   = fmaf(N01, D23, N23 * D01);                            \
            ac3 = fmaf(N, __builtin_amdgcn_rcpf(D01 * D23), ac3);             \
        }                                                                     \
    }

    for (int hc = 0; hc < H_ / 4; hc += 4) {
        if (hc + 4 < H_ / 4) {     // issue next group's kv loads first
            n0 = kp[(long)(hc + 4) * NK_];
            n1 = kp[(long)(hc + 5) * NK_];
            n2 = kp[(long)(hc + 6) * NK_];
            n3 = kp[(long)(hc + 7) * NK_];
        }
        PROC(kv0, hc + 0)
        PROC(kv1, hc + 1)
        PROC(kv2, hc + 2)
        PROC(kv3, hc + 3)
        kv0 = n0; kv1 = n1; kv2 = n2; kv3 = n3;
    }
#undef PROC

    // ---- log-softmax over k, no max pass (|val| <= sum|v| ~ 8, fp32-safe) ----
    __shared__ float red[8][4];
    const int lane = k & 63, wv = k >> 6;
    float acc[4] = {ac0, ac1, ac2, ac3};

    #pragma unroll
    for (int j = 0; j < 4; ++j) {
        float e = __builtin_amdgcn_exp2f(acc[j] * 1.4426950408889634f);
        #pragma unroll
        for (int o = 32; o; o >>= 1) e += __shfl_xor(e, o, 64);
        if (lane == 0) red[wv][j] = e;
    }
    __syncthreads();
    #pragma unroll
    for (int j = 0; j < 4; ++j) {
        float s = 0.f;
        #pragma unroll
        for (int w = 0; w < 8; ++w) s += red[w][j];
        float l = __builtin_amdgcn_logf(s) * 0.6931471805599453f;  // ln(s)
        out[((long)b * NQ_ + q0 + j) * NK_ + k] = acc[j] - l;
    }
}

extern "C" void kernel_launch(void* const* d_in, const int* in_sizes, int n_in,
                              void* d_out, int out_size, void* d_ws, size_t ws_size,
                              hipStream_t stream)
{
    const float* xq = (const float*)d_in[0];  // (4,256,256)
    const float* xk = (const float*)d_in[1];  // (4,512,256)
    const float* w1 = (const float*)d_in[2];  // (256,256) out,in
    const float* w2 = (const float*)d_in[3];  // (256,256)
    const float* v  = (const float*)d_in[4];  // (1,256)
    float* out = (float*)d_out;

    float* ktTan = (float*)d_ws;                          // [4][64][512][4] = 2 MB
    float* tbT   = ktTan + (size_t)B_ * H_ * NK_;         // [4][256][256]   = 1 MB

    gemm_fused<<<dim3(384), 256, 0, stream>>>(xq, xk, w1, w2, ktTan, tbT);
    attn_main<<<dim3(NQ_ / 4, B_), 512, 0, stream>>>(
        (const float4*)ktTan, (const float4*)tbT, (const float4*)v, out);
}